// Round 9
// baseline (327.766 us; speedup 1.0000x reference)
//
#include <hip/hip_runtime.h>
#include <math.h>

// Problem constants: B=2, H=W=64, C=64, N=4096, NUM_LEVELS=4, RADIUS=3 -> K=49
// out: (B, N, 4*49*64) f32 = 102,760,448 floats (411 MB)
// Pyramid in d_ws (f32):
//   L0n: 2*64*64*64 @ 0        (524288 floats)   [normalized fmap2]
//   L1:  2*32*32*64 @ 524288   (131072)
//   L2:  2*16*16*64 @ 655360   ( 32768)
//   L3:  2* 8* 8*64 @ 688128   (  8192)
// float4 base per level l: (524288 - (524288>>2l))/3 = {0,131072,163840,172032}
//
// All levels are computed DIRECTLY from raw fmap2 in ONE kernel:
//  - normalization is per-pixel (channel L2 norm) -> no cross-pixel dependency
//  - L_k's 2x-bilinear cascade composes into a single (4/10/22)-tap separable
//    filter on L0 (weights HW-verified in rounds 4/5, absmax unchanged)

__device__ __forceinline__ float wave_norm_load(const float* __restrict__ raw,
                                                int b, int jy, int jx, int lane) {
  float v = raw[(((b * 64 + jy) * 64) + jx) * 64 + lane];
  float ss = v * v;
  #pragma unroll
  for (int m = 32; m >= 1; m >>= 1) ss += __shfl_xor(ss, m);
  return v / (sqrtf(ss) + 1e-6f);
}

// jax.image.resize 2x bilinear down: taps j=2i-1+t, base {.25,.75,.75,.25},
// out-of-range taps dropped and weights renormalized (per level).
__device__ __forceinline__ void taps4(int i, int S_in, float (&w)[4]) {
  float s = 0.f;
  #pragma unroll
  for (int t = 0; t < 4; t++) {
    int j = 2 * i - 1 + t;
    float bw = (t == 0 || t == 3) ? 0.25f : 0.75f;
    w[t] = (j >= 0 && j < S_in) ? bw : 0.f;
    s += w[t];
  }
  float inv = 1.f / s;
  #pragma unroll
  for (int t = 0; t < 4; t++) w[t] *= inv;
}

// Expand taps over a coarse level (width N at offset jlo) into taps over the
// next finer level (width 2N+2 at offset 2*jlo-1).
template <int N>
__device__ __forceinline__ void expand_taps(int jlo, const float (&win)[N],
                                            int S_in, float (&wout)[2 * N + 2]) {
  #pragma unroll
  for (int t = 0; t < 2 * N + 2; t++) wout[t] = 0.f;
  #pragma unroll
  for (int t = 0; t < N; t++) {
    int i = jlo + t;
    float w4[4];
    float s = 0.f;
    #pragma unroll
    for (int u = 0; u < 4; u++) {
      int j = 2 * i - 1 + u;
      float bw = (u == 0 || u == 3) ? 0.25f : 0.75f;
      w4[u] = (j >= 0 && j < S_in) ? bw : 0.f;
      s += w4[u];
    }
    float inv = (win[t] != 0.f) ? win[t] / s : 0.f;  // guard 0/0 at edges
    #pragma unroll
    for (int u = 0; u < 4; u++) wout[2 * t + u] += w4[u] * inv;
  }
}

// Separable gather on raw fmap2 with inline per-tap-pixel normalization.
// All weights are wave-uniform -> the shfl inside the branch is safe.
template <int NT>
__device__ __forceinline__ float gather2d_n(const float* __restrict__ raw, int b,
                                            int lane, int ylo, int xlo,
                                            const float (&wy)[NT],
                                            const float (&wx)[NT]) {
  float acc = 0.f;
  #pragma unroll
  for (int a = 0; a < NT; a++) {
    if (wy[a] != 0.f) {
      int jy = min(max(ylo + a, 0), 63);
      float racc = 0.f;
      #pragma unroll
      for (int t = 0; t < NT; t++) {
        if (wx[t] != 0.f) {
          int jx = min(max(xlo + t, 0), 63);
          racc += wx[t] * wave_norm_load(raw, b, jy, jx, lane);
        }
      }
      acc += wy[a] * racc;
    }
  }
  return acc;
}

// One kernel, whole pyramid. 10880 waves: [0,8192) L0n, [8192,10240) L1,
// [10240,10752) L2, [10752,10880) L3. lane = channel.
__global__ __launch_bounds__(256) void pyramid_all(
    const float* __restrict__ raw, float* __restrict__ pyr) {
  int gtid = blockIdx.x * 256 + threadIdx.x;
  int lane = gtid & 63;
  int w = gtid >> 6;
  if (w < 8192) {
    // L0n: normalize one pixel per wave
    float v = raw[w * 64 + lane];
    float ss = v * v;
    #pragma unroll
    for (int m = 32; m >= 1; m >>= 1) ss += __shfl_xor(ss, m);
    pyr[w * 64 + lane] = v / (sqrtf(ss) + 1e-6f);
  } else if (w < 10240) {
    int p = w - 8192, b = p >> 10, r = p & 1023, oy = r >> 5, ox = r & 31;
    float wy[4], wx[4];
    taps4(oy, 64, wy);
    taps4(ox, 64, wx);
    float v = gather2d_n<4>(raw, b, lane, 2 * oy - 1, 2 * ox - 1, wy, wx);
    pyr[524288 + p * 64 + lane] = v;
  } else if (w < 10752) {
    int p = w - 10240, b = p >> 8, r = p & 255, oy = r >> 4, ox = r & 15;
    float t4[4], wy[10], wx[10];
    taps4(oy, 32, t4);
    expand_taps<4>(2 * oy - 1, t4, 64, wy);
    taps4(ox, 32, t4);
    expand_taps<4>(2 * ox - 1, t4, 64, wx);
    float v = gather2d_n<10>(raw, b, lane, 4 * oy - 3, 4 * ox - 3, wy, wx);
    pyr[655360 + p * 64 + lane] = v;
  } else if (w < 10880) {
    int p = w - 10752, b = p >> 6, r = p & 63, oy = r >> 3, ox = r & 7;
    float t4[4], t10[10], wy[22], wx[22];
    taps4(oy, 16, t4);
    expand_taps<4>(2 * oy - 1, t4, 32, t10);
    expand_taps<10>(4 * oy - 3, t10, 64, wy);
    taps4(ox, 16, t4);
    expand_taps<4>(2 * ox - 1, t4, 32, t10);
    expand_taps<10>(4 * ox - 3, t10, 64, wx);
    float v = gather2d_n<22>(raw, b, lane, 8 * oy - 7, 8 * ox - 7, wy, wx);
    pyr[688128 + p * 64 + lane] = v;
  }
}

// Register dx-walk sampler (unchanged from round 6): one block per bn=(b,n),
// 448 threads; group g = l*7 + dyi, c4 = t&15; each thread emits 7 float4s,
// reusing the previous x1 texel pair as the next x0 pair.
__global__ __launch_bounds__(448, 4) void corr_sample_reg(
    const float* __restrict__ pyr, const float* __restrict__ coords,
    float* __restrict__ out) {
  unsigned bn = blockIdx.x;  // 0..8191
  unsigned b = bn >> 12;
  int t = threadIdx.x;
  int c4 = t & 15;
  int g = t >> 4;   // 0..27
  int l = g / 7;    // level
  int dyi = g - l * 7;

  int Wl = 64 >> l;
  float sc = 1.0f / (float)(1 << l);  // exact power of two
  float fmx = (float)(Wl - 1);
  unsigned base4 = (524288u - (524288u >> (2 * l))) / 3u;

  float cx = coords[bn * 2 + 0];
  float cy = coords[bn * 2 + 1];
  float cxs = cx * sc, cys = cy * sc;

  // Reference quirk preserved: weights use CLIPPED x1/y1 -> exact zero at edge.
  float y = fminf(fmaxf(cys + (float)(dyi - 3), 0.f), fmx);
  int y0 = (int)floorf(y);
  int y1 = min(y0 + 1, Wl - 1);
  float wy0 = (float)y1 - y;
  float wy1 = y - (float)y0;

  const float4* p4 = (const float4*)pyr;
  unsigned pixb = (unsigned)(b * Wl * Wl);
  unsigned r0 = base4 + ((pixb + (unsigned)(y0 * Wl)) << 4) + (unsigned)c4;
  unsigned r1 = base4 + ((pixb + (unsigned)(y1 * Wl)) << 4) + (unsigned)c4;

  unsigned ob = bn * 3136u + (unsigned)l * 784u + ((unsigned)(dyi * 7) << 4) +
                (unsigned)c4;
  float4* o4 = (float4*)out;

  int px = -1;  // x1 >= 1 always, so -1 never falsely matches
  float4 a0 = make_float4(0.f, 0.f, 0.f, 0.f), a1 = a0;
  #pragma unroll
  for (int dxi = 0; dxi < 7; ++dxi) {
    float x = fminf(fmaxf(cxs + (float)(dxi - 3), 0.f), fmx);
    int x0 = (int)floorf(x);
    int x1 = min(x0 + 1, Wl - 1);
    float wx0 = (float)x1 - x;
    float wx1 = x - (float)x0;

    float4 b0, b1;
    if (x0 == px) {
      b0 = a0; b1 = a1;
    } else {
      b0 = p4[r0 + ((unsigned)x0 << 4)];
      b1 = p4[r1 + ((unsigned)x0 << 4)];
    }
    a0 = p4[r0 + ((unsigned)x1 << 4)];
    a1 = p4[r1 + ((unsigned)x1 << 4)];
    px = x1;

    float4 r;
    r.x = wx0 * (wy0 * b0.x + wy1 * b1.x) + wx1 * (wy0 * a0.x + wy1 * a1.x);
    r.y = wx0 * (wy0 * b0.y + wy1 * b1.y) + wx1 * (wy0 * a0.y + wy1 * a1.y);
    r.z = wx0 * (wy0 * b0.z + wy1 * b1.z) + wx1 * (wy0 * a0.z + wy1 * a1.z);
    r.w = wx0 * (wy0 * b0.w + wy1 * b1.w) + wx1 * (wy0 * a0.w + wy1 * a1.w);
    o4[ob + (unsigned)(dxi << 4)] = r;
  }
}

extern "C" void kernel_launch(void* const* d_in, const int* in_sizes, int n_in,
                              void* d_out, int out_size, void* d_ws, size_t ws_size,
                              hipStream_t stream) {
  // d_in[0] = fmap1 (normalized then discarded by the reference)
  const float* fmap2 = (const float*)d_in[1];
  const float* coords = (const float*)d_in[2];
  float* out = (float*)d_out;
  float* pyr = (float*)d_ws;

  // Whole pyramid in one dispatch: 10880 waves * 64 lanes / 256 = 2720 blocks.
  pyramid_all<<<2720, 256, 0, stream>>>(fmap2, pyr);
  // One block per (b,n): 8192 blocks x 448 threads; no LDS, no barriers.
  corr_sample_reg<<<8192, 448, 0, stream>>>(pyr, coords, out);
}

// Round 10
// 179.922 us; speedup vs baseline: 1.8217x; 1.8217x over previous
//
#include <hip/hip_runtime.h>
#include <math.h>

// Problem constants: B=2, H=W=64, C=64, N=4096, NUM_LEVELS=4, RADIUS=3 -> K=49
// out: (B, N, 4*49*64) f32 = 102,760,448 floats (411 MB)
// Pyramid in d_ws (f32):
//   L0n: 2*64*64*64 @ 0        (524288 floats)   [normalized fmap2]
//   L1:  2*32*32*64 @ 524288   (131072)
//   L2:  2*16*16*64 @ 655360   ( 32768)
//   L3:  2* 8* 8*64 @ 688128   (  8192)
// Barrier counter @ float offset 696320 (byte 2785280), zeroed per call.

#define NBLK 256  // 1 block per CU -> co-residency guaranteed for soft barrier

__device__ __forceinline__ void gridbar(unsigned* __restrict__ cnt, unsigned k) {
  __syncthreads();
  if (threadIdx.x == 0) {
    // RMW release: publish this block's phase writes; RMW goes to coherence pt.
    __hip_atomic_fetch_add(cnt, 1u, __ATOMIC_ACQ_REL, __HIP_MEMORY_SCOPE_AGENT);
    while (__hip_atomic_load(cnt, __ATOMIC_ACQUIRE, __HIP_MEMORY_SCOPE_AGENT) <
           k * (unsigned)NBLK)
      __builtin_amdgcn_s_sleep(1);
  }
  __syncthreads();
  __threadfence();  // agent-scope acquire for all lanes (invalidate stale L1/L2)
}

// One 2x-bilinear-downsample output element (jax.image.resize semantics):
// taps j=2o-1+t, base {.25,.75,.75,.25}, OOR taps dropped + renormalized.
__device__ __forceinline__ float ds_tap(const float* __restrict__ in, int Si,
                                        int b, int oy, int ox, int lane) {
  int xs[4], ys[4];
  float wx[4], wy[4];
  float bw[4] = {0.25f, 0.75f, 0.75f, 0.25f};
  float sx = 0.f, sy = 0.f;
  #pragma unroll
  for (int t = 0; t < 4; t++) {
    int jx = 2 * ox - 1 + t;
    bool vx = (jx >= 0) && (jx < Si);
    xs[t] = vx ? jx : 0;
    wx[t] = vx ? bw[t] : 0.f;
    sx += wx[t];
    int jy = 2 * oy - 1 + t;
    bool vy = (jy >= 0) && (jy < Si);
    ys[t] = vy ? jy : 0;
    wy[t] = vy ? bw[t] : 0.f;
    sy += wy[t];
  }
  float ix = 1.f / sx, iy = 1.f / sy;
  #pragma unroll
  for (int t = 0; t < 4; t++) { wx[t] *= ix; wy[t] *= iy; }
  float acc = 0.f;
  #pragma unroll
  for (int a = 0; a < 4; a++) {
    const float* rp = in + ((b * Si + ys[a]) * Si) * 64 + lane;
    float row = 0.f;
    #pragma unroll
    for (int t = 0; t < 4; t++) row += wx[t] * rp[xs[t] * 64];
    acc += wy[a] * row;
  }
  return acc;
}

// Whole pyramid in ONE dispatch with soft grid barriers between levels.
// 256 blocks x 256 threads = 1024 waves; lane = channel, wave = pixel.
__global__ __launch_bounds__(256) void pyramid_coop(
    const float* __restrict__ raw, float* __restrict__ pyr,
    unsigned* __restrict__ cnt) {
  int lane = threadIdx.x & 63;
  int gw = blockIdx.x * 4 + (threadIdx.x >> 6);  // global wave 0..1023

  // Phase 0: normalize 8192 pixels (channel L2 norm per pixel)
  for (int w = gw; w < 8192; w += 4 * NBLK) {
    float v = raw[w * 64 + lane];
    float ss = v * v;
    #pragma unroll
    for (int m = 32; m >= 1; m >>= 1) ss += __shfl_xor(ss, m);
    pyr[w * 64 + lane] = v / (sqrtf(ss) + 1e-6f);
  }
  gridbar(cnt, 1);

  // Phase 1: L1 (2048 px) from L0n
  for (int p = gw; p < 2048; p += 4 * NBLK) {
    int b = p >> 10, r = p & 1023, oy = r >> 5, ox = r & 31;
    pyr[524288 + p * 64 + lane] = ds_tap(pyr, 64, b, oy, ox, lane);
  }
  gridbar(cnt, 2);

  // Phase 2: L2 (512 px) from L1
  for (int p = gw; p < 512; p += 4 * NBLK) {
    int b = p >> 8, r = p & 255, oy = r >> 4, ox = r & 15;
    pyr[655360 + p * 64 + lane] = ds_tap(pyr + 524288, 32, b, oy, ox, lane);
  }
  gridbar(cnt, 3);

  // Phase 3: L3 (128 px) from L2
  for (int p = gw; p < 128; p += 4 * NBLK) {
    int b = p >> 6, r = p & 63, oy = r >> 3, ox = r & 7;
    pyr[688128 + p * 64 + lane] = ds_tap(pyr + 655360, 16, b, oy, ox, lane);
  }
}

// Register dx-walk sampler (unchanged from round 6): one block per bn=(b,n),
// 448 threads; group g = l*7 + dyi, c4 = t&15; each thread emits 7 float4s,
// reusing the previous x1 texel pair as the next x0 pair.
__global__ __launch_bounds__(448, 4) void corr_sample_reg(
    const float* __restrict__ pyr, const float* __restrict__ coords,
    float* __restrict__ out) {
  unsigned bn = blockIdx.x;  // 0..8191
  unsigned b = bn >> 12;
  int t = threadIdx.x;
  int c4 = t & 15;
  int g = t >> 4;   // 0..27
  int l = g / 7;    // level
  int dyi = g - l * 7;

  int Wl = 64 >> l;
  float sc = 1.0f / (float)(1 << l);  // exact power of two
  float fmx = (float)(Wl - 1);
  unsigned base4 = (524288u - (524288u >> (2 * l))) / 3u;

  float cx = coords[bn * 2 + 0];
  float cy = coords[bn * 2 + 1];
  float cxs = cx * sc, cys = cy * sc;

  // Reference quirk preserved: weights use CLIPPED x1/y1 -> exact zero at edge.
  float y = fminf(fmaxf(cys + (float)(dyi - 3), 0.f), fmx);
  int y0 = (int)floorf(y);
  int y1 = min(y0 + 1, Wl - 1);
  float wy0 = (float)y1 - y;
  float wy1 = y - (float)y0;

  const float4* p4 = (const float4*)pyr;
  unsigned pixb = (unsigned)(b * Wl * Wl);
  unsigned r0 = base4 + ((pixb + (unsigned)(y0 * Wl)) << 4) + (unsigned)c4;
  unsigned r1 = base4 + ((pixb + (unsigned)(y1 * Wl)) << 4) + (unsigned)c4;

  unsigned ob = bn * 3136u + (unsigned)l * 784u + ((unsigned)(dyi * 7) << 4) +
                (unsigned)c4;
  float4* o4 = (float4*)out;

  int px = -1;  // x1 >= 1 always, so -1 never falsely matches
  float4 a0 = make_float4(0.f, 0.f, 0.f, 0.f), a1 = a0;
  #pragma unroll
  for (int dxi = 0; dxi < 7; ++dxi) {
    float x = fminf(fmaxf(cxs + (float)(dxi - 3), 0.f), fmx);
    int x0 = (int)floorf(x);
    int x1 = min(x0 + 1, Wl - 1);
    float wx0 = (float)x1 - x;
    float wx1 = x - (float)x0;

    float4 b0, b1;
    if (x0 == px) {
      b0 = a0; b1 = a1;
    } else {
      b0 = p4[r0 + ((unsigned)x0 << 4)];
      b1 = p4[r1 + ((unsigned)x0 << 4)];
    }
    a0 = p4[r0 + ((unsigned)x1 << 4)];
    a1 = p4[r1 + ((unsigned)x1 << 4)];
    px = x1;

    float4 r;
    r.x = wx0 * (wy0 * b0.x + wy1 * b1.x) + wx1 * (wy0 * a0.x + wy1 * a1.x);
    r.y = wx0 * (wy0 * b0.y + wy1 * b1.y) + wx1 * (wy0 * a0.y + wy1 * a1.y);
    r.z = wx0 * (wy0 * b0.z + wy1 * b1.z) + wx1 * (wy0 * a0.z + wy1 * a1.z);
    r.w = wx0 * (wy0 * b0.w + wy1 * b1.w) + wx1 * (wy0 * a0.w + wy1 * a1.w);
    o4[ob + (unsigned)(dxi << 4)] = r;
  }
}

extern "C" void kernel_launch(void* const* d_in, const int* in_sizes, int n_in,
                              void* d_out, int out_size, void* d_ws, size_t ws_size,
                              hipStream_t stream) {
  // d_in[0] = fmap1 (normalized then discarded by the reference)
  const float* fmap2 = (const float*)d_in[1];
  const float* coords = (const float*)d_in[2];
  float* out = (float*)d_out;
  float* pyr = (float*)d_ws;
  unsigned* cnt = (unsigned*)((char*)d_ws + 2785280);  // after pyramid floats

  // Zero the barrier counter every call (deterministic across graph replays).
  hipMemsetAsync(cnt, 0, 64, stream);
  // Whole pyramid: one dispatch, 3 soft grid barriers, 1 block/CU.
  pyramid_coop<<<NBLK, 256, 0, stream>>>(fmap2, pyr, cnt);
  // One block per (b,n): 8192 blocks x 448 threads; no LDS, no barriers.
  corr_sample_reg<<<8192, 448, 0, stream>>>(pyr, coords, out);
}

// Round 11
// 114.718 us; speedup vs baseline: 2.8571x; 1.5684x over previous
//
#include <hip/hip_runtime.h>
#include <math.h>

// Problem constants: B=2, H=W=64, C=64, N=4096, NUM_LEVELS=4, RADIUS=3 -> K=49
// out: (B, N, 4*49*64) f32 = 102,760,448 floats (411 MB)
// Pyramid in d_ws (f32):
//   L0n: 2*64*64*64 @ 0        (524288 floats)   [normalized fmap2]
//   L1:  2*32*32*64 @ 524288   (131072)
//   L2:  2*16*16*64 @ 655360   ( 32768)
//   L3:  2* 8* 8*64 @ 688128   (  8192)
// Dependency restructure (no barriers, no redundant bulk):
//   A: L0n (8192 waves) and L1 (2048 waves, from RAW with inline norm)
//   B: L2 (512 waves, from L1) and L3 (128 waves, from L1 via composed 10-tap)
//   C: sampler (unchanged round-6 structure)

__device__ __forceinline__ float wave_norm_load(const float* __restrict__ raw,
                                                int b, int jy, int jx, int lane) {
  float v = raw[(((b * 64 + jy) * 64) + jx) * 64 + lane];
  float ss = v * v;
  #pragma unroll
  for (int m = 32; m >= 1; m >>= 1) ss += __shfl_xor(ss, m);
  return v / (sqrtf(ss) + 1e-6f);
}

// jax.image.resize 2x bilinear down: taps j=2i-1+t, base {.25,.75,.75,.25},
// out-of-range taps dropped and weights renormalized.
__device__ __forceinline__ void taps4(int i, int S_in, float (&w)[4]) {
  float s = 0.f;
  #pragma unroll
  for (int t = 0; t < 4; t++) {
    int j = 2 * i - 1 + t;
    float bw = (t == 0 || t == 3) ? 0.25f : 0.75f;
    w[t] = (j >= 0 && j < S_in) ? bw : 0.f;
    s += w[t];
  }
  float inv = 1.f / s;
  #pragma unroll
  for (int t = 0; t < 4; t++) w[t] *= inv;
}

template <int N>
__device__ __forceinline__ void expand_taps(int jlo, const float (&win)[N],
                                            int S_in, float (&wout)[2 * N + 2]) {
  #pragma unroll
  for (int t = 0; t < 2 * N + 2; t++) wout[t] = 0.f;
  #pragma unroll
  for (int t = 0; t < N; t++) {
    int i = jlo + t;
    float w4[4];
    float s = 0.f;
    #pragma unroll
    for (int u = 0; u < 4; u++) {
      int j = 2 * i - 1 + u;
      float bw = (u == 0 || u == 3) ? 0.25f : 0.75f;
      w4[u] = (j >= 0 && j < S_in) ? bw : 0.f;
      s += w4[u];
    }
    float inv = (win[t] != 0.f) ? win[t] / s : 0.f;  // guard 0/0 at edges
    #pragma unroll
    for (int u = 0; u < 4; u++) wout[2 * t + u] += w4[u] * inv;
  }
}

// Separable gather on a stored pyramid level (width Si), clamped taps.
template <int NT>
__device__ __forceinline__ float gather2d_lvl(const float* __restrict__ lvl,
                                              int Si, int b, int lane, int ylo,
                                              int xlo, const float (&wy)[NT],
                                              const float (&wx)[NT]) {
  float acc = 0.f;
  #pragma unroll
  for (int a = 0; a < NT; a++) {
    if (wy[a] != 0.f) {
      int jy = min(max(ylo + a, 0), Si - 1);
      const float* row = lvl + ((b * Si + jy) * Si) * 64 + lane;
      float racc = 0.f;
      #pragma unroll
      for (int t = 0; t < NT; t++) {
        if (wx[t] != 0.f) {
          int jx = min(max(xlo + t, 0), Si - 1);
          racc += wx[t] * row[jx * 64];
        }
      }
      acc += wy[a] * racc;
    }
  }
  return acc;
}

// Kernel A: L0n and L1, both directly from raw fmap2 (independent).
// 10240 waves = 2560 blocks x 256. lane = channel, wave = pixel.
__global__ __launch_bounds__(256) void pyr_a(
    const float* __restrict__ raw, float* __restrict__ pyr) {
  int gtid = blockIdx.x * 256 + threadIdx.x;
  int lane = gtid & 63;
  int w = gtid >> 6;
  if (w < 8192) {
    // L0n: normalize one pixel per wave
    float v = raw[w * 64 + lane];
    float ss = v * v;
    #pragma unroll
    for (int m = 32; m >= 1; m >>= 1) ss += __shfl_xor(ss, m);
    pyr[w * 64 + lane] = v / (sqrtf(ss) + 1e-6f);
  } else {
    // L1 from raw: 4x4 taps with inline per-tap-pixel normalization
    int p = w - 8192;  // 0..2047
    int b = p >> 10, r = p & 1023, oy = r >> 5, ox = r & 31;
    float wy[4], wx[4];
    taps4(oy, 64, wy);
    taps4(ox, 64, wx);
    float acc = 0.f;
    #pragma unroll
    for (int a = 0; a < 4; a++) {
      if (wy[a] != 0.f) {
        int jy = min(max(2 * oy - 1 + a, 0), 63);
        float racc = 0.f;
        #pragma unroll
        for (int t = 0; t < 4; t++) {
          if (wx[t] != 0.f) {
            int jx = min(max(2 * ox - 1 + t, 0), 63);
            racc += wx[t] * wave_norm_load(raw, b, jy, jx, lane);
          }
        }
        acc += wy[a] * racc;
      }
    }
    pyr[524288 + p * 64 + lane] = acc;
  }
}

// Kernel B: L2 (from L1, 4 taps) and L3 (from L1, composed 10 taps) —
// both depend only on L1. 640 waves = 160 blocks x 256.
__global__ __launch_bounds__(256) void pyr_b(float* __restrict__ pyr) {
  const float* L1 = pyr + 524288;
  int gtid = blockIdx.x * 256 + threadIdx.x;
  int lane = gtid & 63;
  int w = gtid >> 6;
  if (w < 512) {
    int p = w, b = p >> 8, r = p & 255, oy = r >> 4, ox = r & 15;
    float wy[4], wx[4];
    taps4(oy, 32, wy);
    taps4(ox, 32, wx);
    float v = gather2d_lvl<4>(L1, 32, b, lane, 2 * oy - 1, 2 * ox - 1, wy, wx);
    pyr[655360 + p * 64 + lane] = v;
  } else {
    int p = w - 512;  // 0..127
    int b = p >> 6, r = p & 63, oy = r >> 3, ox = r & 7;
    float t4[4], wy[10], wx[10];
    taps4(oy, 16, t4);
    expand_taps<4>(2 * oy - 1, t4, 32, wy);
    taps4(ox, 16, t4);
    expand_taps<4>(2 * ox - 1, t4, 32, wx);
    float v = gather2d_lvl<10>(L1, 32, b, lane, 4 * oy - 3, 4 * ox - 3, wy, wx);
    pyr[688128 + p * 64 + lane] = v;
  }
}

// Register dx-walk sampler (unchanged from round 6): one block per bn=(b,n),
// 448 threads; group g = l*7 + dyi, c4 = t&15; each thread emits 7 float4s,
// reusing the previous x1 texel pair as the next x0 pair.
__global__ __launch_bounds__(448, 4) void corr_sample_reg(
    const float* __restrict__ pyr, const float* __restrict__ coords,
    float* __restrict__ out) {
  unsigned bn = blockIdx.x;  // 0..8191
  unsigned b = bn >> 12;
  int t = threadIdx.x;
  int c4 = t & 15;
  int g = t >> 4;   // 0..27
  int l = g / 7;    // level
  int dyi = g - l * 7;

  int Wl = 64 >> l;
  float sc = 1.0f / (float)(1 << l);  // exact power of two
  float fmx = (float)(Wl - 1);
  unsigned base4 = (524288u - (524288u >> (2 * l))) / 3u;

  float cx = coords[bn * 2 + 0];
  float cy = coords[bn * 2 + 1];
  float cxs = cx * sc, cys = cy * sc;

  // Reference quirk preserved: weights use CLIPPED x1/y1 -> exact zero at edge.
  float y = fminf(fmaxf(cys + (float)(dyi - 3), 0.f), fmx);
  int y0 = (int)floorf(y);
  int y1 = min(y0 + 1, Wl - 1);
  float wy0 = (float)y1 - y;
  float wy1 = y - (float)y0;

  const float4* p4 = (const float4*)pyr;
  unsigned pixb = (unsigned)(b * Wl * Wl);
  unsigned r0 = base4 + ((pixb + (unsigned)(y0 * Wl)) << 4) + (unsigned)c4;
  unsigned r1 = base4 + ((pixb + (unsigned)(y1 * Wl)) << 4) + (unsigned)c4;

  unsigned ob = bn * 3136u + (unsigned)l * 784u + ((unsigned)(dyi * 7) << 4) +
                (unsigned)c4;
  float4* o4 = (float4*)out;

  int px = -1;  // x1 >= 1 always, so -1 never falsely matches
  float4 a0 = make_float4(0.f, 0.f, 0.f, 0.f), a1 = a0;
  #pragma unroll
  for (int dxi = 0; dxi < 7; ++dxi) {
    float x = fminf(fmaxf(cxs + (float)(dxi - 3), 0.f), fmx);
    int x0 = (int)floorf(x);
    int x1 = min(x0 + 1, Wl - 1);
    float wx0 = (float)x1 - x;
    float wx1 = x - (float)x0;

    float4 b0, b1;
    if (x0 == px) {
      b0 = a0; b1 = a1;
    } else {
      b0 = p4[r0 + ((unsigned)x0 << 4)];
      b1 = p4[r1 + ((unsigned)x0 << 4)];
    }
    a0 = p4[r0 + ((unsigned)x1 << 4)];
    a1 = p4[r1 + ((unsigned)x1 << 4)];
    px = x1;

    float4 r;
    r.x = wx0 * (wy0 * b0.x + wy1 * b1.x) + wx1 * (wy0 * a0.x + wy1 * a1.x);
    r.y = wx0 * (wy0 * b0.y + wy1 * b1.y) + wx1 * (wy0 * a0.y + wy1 * a1.y);
    r.z = wx0 * (wy0 * b0.z + wy1 * b1.z) + wx1 * (wy0 * a0.z + wy1 * a1.z);
    r.w = wx0 * (wy0 * b0.w + wy1 * b1.w) + wx1 * (wy0 * a0.w + wy1 * a1.w);
    o4[ob + (unsigned)(dxi << 4)] = r;
  }
}

extern "C" void kernel_launch(void* const* d_in, const int* in_sizes, int n_in,
                              void* d_out, int out_size, void* d_ws, size_t ws_size,
                              hipStream_t stream) {
  // d_in[0] = fmap1 (normalized then discarded by the reference)
  const float* fmap2 = (const float*)d_in[1];
  const float* coords = (const float*)d_in[2];
  float* out = (float*)d_out;
  float* pyr = (float*)d_ws;

  // A: L0n + L1 (both from raw). 10240 waves = 2560 blocks.
  pyr_a<<<2560, 256, 0, stream>>>(fmap2, pyr);
  // B: L2 + L3 (both from L1). 640 waves = 160 blocks.
  pyr_b<<<160, 256, 0, stream>>>(pyr);
  // C: sampler. One block per (b,n): 8192 blocks x 448 threads.
  corr_sample_reg<<<8192, 448, 0, stream>>>(pyr, coords, out);
}